// Round 3
// baseline (352.429 us; speedup 1.0000x reference)
//
#include <hip/hip_runtime.h>
#include <hip/hip_bf16.h>
#include <math.h>

#define B_ 16
#define D_ 512
#define N_ 4096   // H*W
#define K_ 64

typedef __attribute__((ext_vector_type(8))) short bfrag;   // 8 bf16 = 4 VGPRs
typedef __attribute__((ext_vector_type(4))) float f32x4;

static __device__ __forceinline__ float bf2f(unsigned short u) {
    return __uint_as_float(((unsigned)u) << 16);
}
static __device__ __forceinline__ unsigned short f2bf(float v) {
    __hip_bfloat16 h = __float2bfloat16(v);   // RNE
    union { __hip_bfloat16 h; unsigned short u; } cv; cv.h = h; return cv.u;
}
static __device__ __forceinline__ void split3(float v, unsigned short& h,
                                              unsigned short& m, unsigned short& l) {
    h = f2bf(v); float r1 = v - bf2f(h);
    m = f2bf(r1); float r2 = r1 - bf2f(m);
    l = f2bf(r2);
}
static __device__ __forceinline__ void split2(float v, unsigned short& h,
                                              unsigned short& l) {
    h = f2bf(v); l = f2bf(v - bf2f(h));
}
#define MFMA(a, b, c) __builtin_amdgcn_mfma_f32_16x16x32_bf16((a), (b), (c), 0, 0, 0)

// xf: f32 x-tile [512 d][32 n], pitch exactly 32 (no pad). Row stride = 128 B
// == 0 mod banks, so 4-float chunks are rotated by d: chunk' = (chunk - d) & 7.
// Staging writes (32 lanes span n at fixed d) stay a full-row permutation;
// phase-C reads (rows d = base + c, chunks 2q/2q+1) spread evenly: rows c and
// c+8 alias -> 2-way (free, m136).
static __device__ __forceinline__ int xf_idx(int d, int n) {
    return d * 32 + ((((n >> 2) - d) & 7) << 2) + (n & 3);
}

// ---------------------------------------------------------------------------
// K0: pre-split conv_w into 3 bf16 limb planes [lv][64][512] (192 KB total).
// ---------------------------------------------------------------------------
__global__ __launch_bounds__(256) void k_prep(
    const float* __restrict__ conv_w, unsigned short* __restrict__ cwL)
{
    const int i = blockIdx.x * 256 + threadIdx.x;
    const float4 v = *(const float4*)&conv_w[i * 4];
    const float vv[4] = {v.x, v.y, v.z, v.w};
    unsigned short h[4], m[4], l[4];
    #pragma unroll
    for (int j = 0; j < 4; ++j) split3(vv[j], h[j], m[j], l[j]);
    *(ushort4*)&cwL[0 * (K_ * D_) + i * 4] = make_ushort4(h[0], h[1], h[2], h[3]);
    *(ushort4*)&cwL[1 * (K_ * D_) + i * 4] = make_ushort4(m[0], m[1], m[2], m[3]);
    *(ushort4*)&cwL[2 * (K_ * D_) + i * 4] = make_ushort4(l[0], l[1], l[2], l[3]);
}

// ---------------------------------------------------------------------------
// F2: fused logits + softmax + wsum + w.x^T — 2 blocks/CU version.
// Grid 512 = B x 32 n-groups (2 blocks/CU), 512 threads = 8 waves (4 kw x 2 nh).
// n-sub-tile = 32 (t-loop x4 covers 128 n per block). LDS 79,360 B:
//   xf   f32 [512][32] swizzled      0 .. 65,536
//   xsb  u16 [3][32][72] (64d step)  65,536 .. 79,360   (phase A limbs)
//   wsb  u16 [2][64][40]  alias      65,536 .. 75,776   (phase B/C w limbs)
//   redm/reds f32 [4][32] each       75,776 .. 76,800
// Per 64-d step: stage 64x32 x (4 f32/thread) -> split3 limbs + f32 copy ->
// barrier -> 12 MFMA/wave -> barrier. Phase B softmax in LDS; phase C
// contracts the 32-n tile from xf (split2 on the fly), acc2 16k x 256d/wave.
// ---------------------------------------------------------------------------
__global__ __launch_bounds__(512, 4) void k_fused(
    const float* __restrict__ x, const unsigned short* __restrict__ cwL,
    const float* __restrict__ conv_b, float* __restrict__ vlad_part,
    float* __restrict__ wsumbuf)
{
    const int b    = blockIdx.x >> 5;
    const int g    = blockIdx.x & 31;          // n-group: n in [g*128, g*128+128)
    const int tid  = threadIdx.x;
    const int w    = tid >> 6;
    const int lane = tid & 63;
    const int q    = lane >> 4;
    const int c    = lane & 15;
    const int kw   = w >> 1;                   // k-quarter (16 k per wave)
    const int nh   = w & 1;                    // n-half (A/B) / d-half (C)
    const int sn   = tid & 31;                 // staging n
    const int sg   = tid >> 5;                 // staging d-group (4 rows)

    extern __shared__ char smem[];
    float*          xf   = (float*)smem;                       // [512][32] swz
    unsigned short* xsb  = (unsigned short*)(smem + 65536);    // [3][32][72]
    unsigned short* wsb  = (unsigned short*)(smem + 65536);    // [2][64][40] alias
    float*          redm = (float*)(smem + 75776);             // [4][32]
    float*          reds = (float*)(smem + 76288);             // [4][32]

    f32x4 acc2[16];                            // wx accumulator: 16k x 256d / wave
    #pragma unroll
    for (int i = 0; i < 16; ++i) acc2[i] = (f32x4){0.f, 0.f, 0.f, 0.f};
    float wacc[4] = {0.f, 0.f, 0.f, 0.f};
    float bias[4];
    #pragma unroll
    for (int r = 0; r < 4; ++r) bias[r] = conv_b[kw * 16 + q * 4 + r];

    const unsigned short* cwp = cwL + (kw * 16 + c) * D_ + q * 8;
    const int nloc = nh * 16 + c;

    #pragma unroll 1
    for (int t = 0; t < 4; ++t) {
        const float* xb = x + (size_t)b * ((size_t)D_ * N_) + (g * 128 + t * 32) + sn;

        f32x4 accA = (f32x4){0.f, 0.f, 0.f, 0.f};

        // ---- phase A: stage x (f32 + 3-limb) + logits MFMA, 64-d steps
        float gx[4];
        #pragma unroll
        for (int r = 0; r < 4; ++r) gx[r] = xb[(size_t)(sg * 4 + r) * N_];

        #pragma unroll 1
        for (int d0 = 0; d0 < D_; d0 += 64) {
            bfrag af[2][3];
            #pragma unroll
            for (int h = 0; h < 2; ++h)
                #pragma unroll
                for (int lv = 0; lv < 3; ++lv)
                    af[h][lv] = *(const bfrag*)(cwp + lv * (K_ * D_) + d0 + h * 32);
            const int dn = (d0 + 64) & (D_ - 1);   // wraps (unused last iter)
            float nx[4];
            #pragma unroll
            for (int r = 0; r < 4; ++r) nx[r] = xb[(size_t)(dn + sg * 4 + r) * N_];

            unsigned short h4[4], m4[4], l4[4];
            #pragma unroll
            for (int r = 0; r < 4; ++r) {
                xf[xf_idx(d0 + sg * 4 + r, sn)] = gx[r];
                split3(gx[r], h4[r], m4[r], l4[r]);
            }
            {
                const int o = sn * 72 + sg * 4;
                *(ushort4*)&xsb[o]        = make_ushort4(h4[0], h4[1], h4[2], h4[3]);
                *(ushort4*)&xsb[2304 + o] = make_ushort4(m4[0], m4[1], m4[2], m4[3]);
                *(ushort4*)&xsb[4608 + o] = make_ushort4(l4[0], l4[1], l4[2], l4[3]);
            }
            __syncthreads();
            #pragma unroll
            for (int h = 0; h < 2; ++h) {
                const int ro = nloc * 72 + h * 32 + q * 8;
                const bfrag bf0 = *(const bfrag*)&xsb[ro];
                const bfrag bf1 = *(const bfrag*)&xsb[2304 + ro];
                const bfrag bf2 = *(const bfrag*)&xsb[4608 + ro];
                accA = MFMA(af[h][0], bf0, accA);   // hh
                accA = MFMA(af[h][0], bf1, accA);   // hm
                accA = MFMA(af[h][1], bf0, accA);   // mh
                accA = MFMA(af[h][1], bf1, accA);   // mm
                accA = MFMA(af[h][0], bf2, accA);   // hl
                accA = MFMA(af[h][2], bf0, accA);   // lh
            }
            __syncthreads();
            #pragma unroll
            for (int r = 0; r < 4; ++r) gx[r] = nx[r];
        }

        // ---- phase B: bias + cross-wave softmax (lane: k=kw*16+q*4+r, n=nloc)
        #pragma unroll
        for (int r = 0; r < 4; ++r) accA[r] += bias[r];

        float mm = fmaxf(fmaxf(accA[0], accA[1]), fmaxf(accA[2], accA[3]));
        mm = fmaxf(mm, __shfl_xor(mm, 16));
        mm = fmaxf(mm, __shfl_xor(mm, 32));
        if (q == 0) redm[kw * 32 + nloc] = mm;
        __syncthreads();
        const float mall = fmaxf(fmaxf(redm[nloc], redm[32 + nloc]),
                                 fmaxf(redm[64 + nloc], redm[96 + nloc]));
        float sl = 0.f;
        #pragma unroll
        for (int r = 0; r < 4; ++r) {
            const float e = __expf(accA[r] - mall);
            accA[r] = e;
            sl += e;
        }
        sl += __shfl_xor(sl, 16);
        sl += __shfl_xor(sl, 32);
        if (q == 0) reds[kw * 32 + nloc] = sl;
        __syncthreads();
        const float inv = 1.0f / (reds[nloc] + reds[32 + nloc] +
                                  reds[64 + nloc] + reds[96 + nloc]);
        #pragma unroll
        for (int r = 0; r < 4; ++r) {
            const float v = accA[r] * inv;
            unsigned short hi, lo;
            split2(v, hi, lo);
            const int k = kw * 16 + q * 4 + r;
            wsb[k * 40 + nloc]        = hi;    // xsb dead; alias safe
            wsb[2560 + k * 40 + nloc] = lo;
            wacc[r] += v;
        }
        __syncthreads();   // ws visible to all waves

        // ---- phase C: wx += w . x^T from LDS, barrier-free, 2-limb
        const bfrag awh = *(const bfrag*)&wsb[(kw * 16 + c) * 40 + q * 8];
        const bfrag awl = *(const bfrag*)&wsb[2560 + (kw * 16 + c) * 40 + q * 8];
        #pragma unroll
        for (int i = 0; i < 16; ++i) {
            const int row = i * 32 + nh * 16 + c;   // d-row
            const int rb  = row * 32;
            const float4 v0 = *(const float4*)&xf[rb + (((2 * q     - row) & 7) << 2)];
            const float4 v1 = *(const float4*)&xf[rb + (((2 * q + 1 - row) & 7) << 2)];
            const float vv[8] = {v0.x, v0.y, v0.z, v0.w, v1.x, v1.y, v1.z, v1.w};
            bfrag bh, bl;
            #pragma unroll
            for (int j = 0; j < 8; ++j) {
                unsigned short hh, ll;
                split2(vv[j], hh, ll);
                bh[j] = (short)hh;
                bl[j] = (short)ll;
            }
            f32x4 a = acc2[i];
            a = MFMA(awh, bh, a);
            a = MFMA(awh, bl, a);
            a = MFMA(awl, bh, a);
            acc2[i] = a;
        }
        __syncthreads();   // protect xf/wsb before next sub-tile overwrites
    }

    // ---- wsum: reduce over c-lanes, one atomic per (k, wave)
    #pragma unroll
    for (int msk = 1; msk < 16; msk <<= 1)
        #pragma unroll
        for (int r = 0; r < 4; ++r) wacc[r] += __shfl_xor(wacc[r], msk);
    if (c == 0)
        #pragma unroll
        for (int r = 0; r < 4; ++r)
            atomicAdd(&wsumbuf[b * K_ + kw * 16 + q * 4 + r], wacc[r]);

    // ---- partial store (no atomics)
    float* vp = vlad_part + ((size_t)(b * 32 + g) * K_) * D_;
    #pragma unroll
    for (int i = 0; i < 16; ++i)
        #pragma unroll
        for (int r = 0; r < 4; ++r)
            vp[(size_t)(kw * 16 + q * 4 + r) * D_ + i * 32 + nh * 16 + c] = acc2[i][r];
}

// ---------------------------------------------------------------------------
// K3: reduce 32 n-group partials; v = vlad - wsum*c; row L2; global /8.
// ---------------------------------------------------------------------------
__global__ __launch_bounds__(256) void k_norm(
    const float* __restrict__ wsumbuf, const float* __restrict__ vlad_part,
    const float* __restrict__ centers, float* __restrict__ out)
{
    const int b   = blockIdx.x >> 6;
    const int k   = blockIdx.x & 63;
    const int tid = threadIdx.x;

    const float wsum = wsumbuf[b * K_ + k];

    const float* vp = vlad_part + ((size_t)(b * 32) * K_ + k) * D_;
    float a0 = 0.f, a1 = 0.f;
    #pragma unroll 4
    for (int gg = 0; gg < 32; ++gg) {
        a0 += vp[(size_t)gg * K_ * D_ + tid];
        a1 += vp[(size_t)gg * K_ * D_ + tid + 256];
    }
    const float* cr = centers + k * D_;
    const float v0 = a0 - wsum * cr[tid];
    const float v1 = a1 - wsum * cr[tid + 256];

    float ss = v0 * v0 + v1 * v1;
    __shared__ float red2[4];
    #pragma unroll
    for (int off = 32; off > 0; off >>= 1) ss += __shfl_down(ss, off, 64);
    if ((tid & 63) == 0) red2[tid >> 6] = ss;
    __syncthreads();
    const float nrm = sqrtf(red2[0] + red2[1] + red2[2] + red2[3]);
    const float scale = 1.0f / (8.0f * fmaxf(nrm, 1e-12f));

    float* outr = out + ((size_t)b * K_ + k) * D_;
    outr[tid]       = v0 * scale;
    outr[tid + 256] = v1 * scale;
}

extern "C" void kernel_launch(void* const* d_in, const int* in_sizes, int n_in,
                              void* d_out, int out_size, void* d_ws, size_t ws_size,
                              hipStream_t stream) {
    const float* x       = (const float*)d_in[0];
    const float* conv_w  = (const float*)d_in[1];
    const float* conv_b  = (const float*)d_in[2];
    const float* centers = (const float*)d_in[3];
    float* out = (float*)d_out;

    char* wsp = (char*)d_ws;
    float* vlad_part    = (float*)wsp;                               // 64 MiB
    float* wsumbuf      = (float*)(wsp + (64u << 20));               // 4 KiB
    unsigned short* cwL = (unsigned short*)(wsp + (64u << 20) + (1u << 16)); // 192 KiB

    hipMemsetAsync(wsumbuf, 0, B_ * K_ * sizeof(float), stream);

    static bool attr_set = false;
    if (!attr_set) {   // 77.5 KB dynamic LDS -> 2 blocks/CU
        (void)hipFuncSetAttribute((const void*)k_fused,
                                  hipFuncAttributeMaxDynamicSharedMemorySize, 79360);
        attr_set = true;
    }

    k_prep<<<32, 256, 0, stream>>>(conv_w, cwL);
    k_fused<<<B_ * 32, 512, 79360, stream>>>(x, cwL, conv_b, vlad_part, wsumbuf);
    k_norm<<<B_ * K_, 256, 0, stream>>>(wsumbuf, vlad_part, centers, out);
}

// Round 4
// 307.659 us; speedup vs baseline: 1.1455x; 1.1455x over previous
//
#include <hip/hip_runtime.h>
#include <hip/hip_bf16.h>
#include <math.h>

#define B_ 16
#define D_ 512
#define N_ 4096   // H*W
#define K_ 64

typedef __attribute__((ext_vector_type(8))) short bfrag;   // 8 bf16 = 4 VGPRs
typedef __attribute__((ext_vector_type(4))) float f32x4;

static __device__ __forceinline__ float bf2f(unsigned short u) {
    return __uint_as_float(((unsigned)u) << 16);
}
static __device__ __forceinline__ unsigned short f2bf(float v) {
    __hip_bfloat16 h = __float2bfloat16(v);   // RNE
    union { __hip_bfloat16 h; unsigned short u; } cv; cv.h = h; return cv.u;
}
static __device__ __forceinline__ void split3(float v, unsigned short& h,
                                              unsigned short& m, unsigned short& l) {
    h = f2bf(v); float r1 = v - bf2f(h);
    m = f2bf(r1); float r2 = r1 - bf2f(m);
    l = f2bf(r2);
}
static __device__ __forceinline__ void split2(float v, unsigned short& h,
                                              unsigned short& l) {
    h = f2bf(v); l = f2bf(v - bf2f(h));
}
#define MFMA(a, b, c) __builtin_amdgcn_mfma_f32_16x16x32_bf16((a), (b), (c), 0, 0, 0)

// ws (w limbs [64 k][64 n]): row pitch 72 shorts; 8-short chunks rotated by k
// -> phase-C bfrag reads land 2-way max (measured fine in the 112 us run).
static __device__ __forceinline__ int ws_idx(int k, int n) {
    const int CH  = n >> 3;
    const int CHs = (CH - 2 * (k & 7)) & 7;
    return k * 72 + CHs * 8 + (n & 7);
}

// ---------------------------------------------------------------------------
// K0: pre-split conv_w into 3 bf16 limb planes [lv][64][512] (192 KB total).
// ---------------------------------------------------------------------------
__global__ __launch_bounds__(256) void k_prep(
    const float* __restrict__ conv_w, unsigned short* __restrict__ cwL)
{
    const int i = blockIdx.x * 256 + threadIdx.x;
    const float4 v = *(const float4*)&conv_w[i * 4];
    const float vv[4] = {v.x, v.y, v.z, v.w};
    unsigned short h[4], m[4], l[4];
    #pragma unroll
    for (int j = 0; j < 4; ++j) split3(vv[j], h[j], m[j], l[j]);
    *(ushort4*)&cwL[0 * (K_ * D_) + i * 4] = make_ushort4(h[0], h[1], h[2], h[3]);
    *(ushort4*)&cwL[1 * (K_ * D_) + i * 4] = make_ushort4(m[0], m[1], m[2], m[3]);
    *(ushort4*)&cwL[2 * (K_ * D_) + i * 4] = make_ushort4(l[0], l[1], l[2], l[3]);
}

// ---------------------------------------------------------------------------
// F3: fused kernel, F1 geometry (grid 256 = B x 16 n-groups, 64-n sub-tiles),
// with two changes vs the 112 us F1:
//  (1) phase A uses RAW s_barrier + lgkmcnt(0)-only waits (T3/T4): global
//      prefetch loads (x: 2 steps deep, cw frags: 1 step) stay in flight
//      across barriers; the compiler emits counted vmcnt at first use.
//      No more vmcnt(0) drain per step.
//  (2) x is staged for phase C as h/m bf16 LIMB PLANES [512][68] (split3's
//      h,m == split2 of f32, bit-identical), so phase C is pure LDS b128
//      reads + MFMA, no per-element split2 VALU.
// LDS 159,744 B: Lh 69,632 | Lm 69,632 | xsb 15,360 (alias wsb 18,432) |
// redm/reds 2 x 1,024.
// ---------------------------------------------------------------------------
__global__ __launch_bounds__(512, 2) void k_fused(
    const float* __restrict__ x, const unsigned short* __restrict__ cwL,
    const float* __restrict__ conv_b, float* __restrict__ vlad_part,
    float* __restrict__ wsumbuf)
{
    const int b    = blockIdx.x >> 4;
    const int g    = blockIdx.x & 15;          // n-group: n in [g*256, g*256+256)
    const int tid  = threadIdx.x;
    const int w    = tid >> 6;
    const int lane = tid & 63;
    const int q    = lane >> 4;
    const int c    = lane & 15;
    const int kw   = w >> 1;                   // k-quarter (16 k per wave)
    const int nw   = w & 1;                    // n-half (phase A) / d-half (C)
    const int dsub = w * 4;                    // staging d-rows per wave

    extern __shared__ char smem[];
    unsigned short* Lh   = (unsigned short*)smem;                 // [512][68]
    unsigned short* Lm   = (unsigned short*)(smem + 69632);       // [512][68]
    unsigned short* xsb  = (unsigned short*)(smem + 139264);      // [3][64][40]
    unsigned short* wsb  = (unsigned short*)(smem + 139264);      // [2][64][72] alias
    float*          redm = (float*)(smem + 157696);               // [4][64]
    float*          reds = (float*)(smem + 158720);               // [4][64]

    f32x4 acc2[16];                            // wx accumulator: 16k x 256d / wave
    #pragma unroll
    for (int i = 0; i < 16; ++i) acc2[i] = (f32x4){0.f, 0.f, 0.f, 0.f};
    float wacc[4] = {0.f, 0.f, 0.f, 0.f};
    float bias[4];
    #pragma unroll
    for (int r = 0; r < 4; ++r) bias[r] = conv_b[kw * 16 + q * 4 + r];

    const unsigned short* cwp = cwL + (kw * 16 + c) * D_ + q * 8;

    #pragma unroll 1
    for (int t = 0; t < 4; ++t) {
        const int gn0 = g * 256 + t * 64;
        const float* xb = x + (size_t)b * ((size_t)D_ * N_) + gn0 + lane;

        f32x4 accA[2];
        accA[0] = (f32x4){0.f, 0.f, 0.f, 0.f};
        accA[1] = (f32x4){0.f, 0.f, 0.f, 0.f};

        // ---- phase A: raw-barrier pipelined staging + 3-limb logits MFMA
        float gxb[3][4];                       // x prefetch, depth 2
        bfrag afb[2][3];                       // cw frag prefetch, depth 1

        #pragma unroll
        for (int r = 0; r < 4; ++r) gxb[0][r] = xb[(size_t)(dsub + r) * N_];
        #pragma unroll
        for (int lv = 0; lv < 3; ++lv)
            afb[0][lv] = *(const bfrag*)(cwp + lv * (K_ * D_));
        #pragma unroll
        for (int r = 0; r < 4; ++r) gxb[1][r] = xb[(size_t)(32 + dsub + r) * N_];

        #pragma unroll
        for (int s = 0; s < 16; ++s) {
            const int d0 = s * 32;
            // issue next cw frags (older than x prefetch below -> FIFO ok)
            if (s < 15) {
                #pragma unroll
                for (int lv = 0; lv < 3; ++lv)
                    afb[(s + 1) & 1][lv] =
                        *(const bfrag*)(cwp + lv * (K_ * D_) + (s + 1) * 32);
            }
            // issue x loads for step s+2
            if (s < 14) {
                #pragma unroll
                for (int r = 0; r < 4; ++r)
                    gxb[(s + 2) % 3][r] =
                        xb[(size_t)((s + 2) * 32 + dsub + r) * N_];
            }
            // stage step s (waits only on gxb[s%3]; newer loads stay in flight)
            unsigned short h4[4], m4[4], l4[4];
            #pragma unroll
            for (int r = 0; r < 4; ++r) {
                split3(gxb[s % 3][r], h4[r], m4[r], l4[r]);
                Lh[(d0 + dsub + r) * 68 + lane] = h4[r];
                Lm[(d0 + dsub + r) * 68 + lane] = m4[r];
            }
            {
                const int Cs  = (dsub >> 3) ^ ((lane >> 3) & 3);
                const int dsw = Cs * 8 + (dsub & 7);
                *(ushort4*)&xsb[0 * 2560 + lane * 40 + dsw] = make_ushort4(h4[0], h4[1], h4[2], h4[3]);
                *(ushort4*)&xsb[1 * 2560 + lane * 40 + dsw] = make_ushort4(m4[0], m4[1], m4[2], m4[3]);
                *(ushort4*)&xsb[2 * 2560 + lane * 40 + dsw] = make_ushort4(l4[0], l4[1], l4[2], l4[3]);
            }
            asm volatile("s_waitcnt lgkmcnt(0)" ::: "memory");
            __builtin_amdgcn_sched_barrier(0);
            __builtin_amdgcn_s_barrier();          // writes visible; vmcnt NOT drained
            __builtin_amdgcn_sched_barrier(0);
            #pragma unroll
            for (int nt = 0; nt < 2; ++nt) {
                const int row = nw * 32 + nt * 16 + c;
                const int qs  = (q ^ ((row >> 3) & 3)) * 8;
                const bfrag bf0 = *(const bfrag*)&xsb[0 * 2560 + row * 40 + qs];
                const bfrag bf1 = *(const bfrag*)&xsb[1 * 2560 + row * 40 + qs];
                const bfrag bf2 = *(const bfrag*)&xsb[2 * 2560 + row * 40 + qs];
                f32x4 a = accA[nt];
                a = MFMA(afb[s & 1][0], bf0, a);   // hh
                a = MFMA(afb[s & 1][0], bf1, a);   // hm
                a = MFMA(afb[s & 1][1], bf0, a);   // mh
                a = MFMA(afb[s & 1][1], bf1, a);   // mm
                a = MFMA(afb[s & 1][0], bf2, a);   // hl
                a = MFMA(afb[s & 1][2], bf0, a);   // lh
                accA[nt] = a;
            }
            asm volatile("s_waitcnt lgkmcnt(0)" ::: "memory");
            __builtin_amdgcn_sched_barrier(0);
            __builtin_amdgcn_s_barrier();          // reads done; safe to overwrite
            __builtin_amdgcn_sched_barrier(0);
        }

        // ---- phase B: bias + cross-wave softmax (lane: k=kw*16+q*4+r)
        #pragma unroll
        for (int nt = 0; nt < 2; ++nt)
            #pragma unroll
            for (int r = 0; r < 4; ++r) accA[nt][r] += bias[r];

        {
            float ml[2];
            #pragma unroll
            for (int nt = 0; nt < 2; ++nt) {
                float mm = fmaxf(fmaxf(accA[nt][0], accA[nt][1]),
                                 fmaxf(accA[nt][2], accA[nt][3]));
                mm = fmaxf(mm, __shfl_xor(mm, 16));
                mm = fmaxf(mm, __shfl_xor(mm, 32));
                ml[nt] = mm;
            }
            if (q == 0) {
                redm[kw * 64 + nw * 32 + c]      = ml[0];
                redm[kw * 64 + nw * 32 + 16 + c] = ml[1];
            }
        }
        __syncthreads();
        float mall[2];
        #pragma unroll
        for (int nt = 0; nt < 2; ++nt) {
            const int n = nw * 32 + nt * 16 + c;
            mall[nt] = fmaxf(fmaxf(redm[n], redm[64 + n]),
                             fmaxf(redm[128 + n], redm[192 + n]));
        }
        float sl[2] = {0.f, 0.f};
        #pragma unroll
        for (int nt = 0; nt < 2; ++nt) {
            #pragma unroll
            for (int r = 0; r < 4; ++r) {
                const float e = __expf(accA[nt][r] - mall[nt]);
                accA[nt][r] = e;
                sl[nt] += e;
            }
            sl[nt] += __shfl_xor(sl[nt], 16);
            sl[nt] += __shfl_xor(sl[nt], 32);
        }
        if (q == 0) {
            reds[kw * 64 + nw * 32 + c]      = sl[0];
            reds[kw * 64 + nw * 32 + 16 + c] = sl[1];
        }
        __syncthreads();
        #pragma unroll
        for (int nt = 0; nt < 2; ++nt) {
            const int n = nw * 32 + nt * 16 + c;
            const float inv = 1.0f / (reds[n] + reds[64 + n] + reds[128 + n] + reds[192 + n]);
            #pragma unroll
            for (int r = 0; r < 4; ++r) {
                const float v = accA[nt][r] * inv;
                unsigned short hi, lo;
                split2(v, hi, lo);
                const int k = kw * 16 + q * 4 + r;
                wsb[ws_idx(k, n)]        = hi;     // xsb dead; alias is safe
                wsb[4608 + ws_idx(k, n)] = lo;
                wacc[r] += v;
            }
        }
        __syncthreads();   // ws visible to all waves

        // ---- phase C: wx += w . x^T from LDS limb planes, barrier-free
        bfrag awh[2], awl[2];
        #pragma unroll
        for (int ns = 0; ns < 2; ++ns) {
            awh[ns] = *(const bfrag*)&wsb[ws_idx(kw * 16 + c, ns * 32 + q * 8)];
            awl[ns] = *(const bfrag*)&wsb[4608 + ws_idx(kw * 16 + c, ns * 32 + q * 8)];
        }
        #pragma unroll
        for (int i = 0; i < 16; ++i) {
            const int row = i * 32 + nw * 16 + c;   // d-row
            f32x4 a = acc2[i];
            #pragma unroll
            for (int ns = 0; ns < 2; ++ns) {
                const bfrag bh = *(const bfrag*)&Lh[row * 68 + ns * 32 + q * 8];
                const bfrag bl = *(const bfrag*)&Lm[row * 68 + ns * 32 + q * 8];
                a = MFMA(awh[ns], bh, a);
                a = MFMA(awh[ns], bl, a);
                a = MFMA(awl[ns], bh, a);
            }
            acc2[i] = a;
        }
        __syncthreads();   // protect Lh/Lm/wsb before next sub-tile overwrites
    }

    // ---- wsum: reduce over c-lanes, one atomic per (k, wave)
    #pragma unroll
    for (int msk = 1; msk < 16; msk <<= 1)
        #pragma unroll
        for (int r = 0; r < 4; ++r) wacc[r] += __shfl_xor(wacc[r], msk);
    if (c == 0)
        #pragma unroll
        for (int r = 0; r < 4; ++r)
            atomicAdd(&wsumbuf[b * K_ + kw * 16 + q * 4 + r], wacc[r]);

    // ---- partial store (coalesced along d, no atomics)
    float* vp = vlad_part + ((size_t)(b * 16 + g) * K_) * D_;
    #pragma unroll
    for (int i = 0; i < 16; ++i)
        #pragma unroll
        for (int r = 0; r < 4; ++r)
            vp[(size_t)(kw * 16 + q * 4 + r) * D_ + i * 32 + nw * 16 + c] = acc2[i][r];
}

// ---------------------------------------------------------------------------
// K3: reduce 16 n-group partials; v = vlad - wsum*c; row L2; global /8.
// ---------------------------------------------------------------------------
__global__ __launch_bounds__(256) void k_norm(
    const float* __restrict__ wsumbuf, const float* __restrict__ vlad_part,
    const float* __restrict__ centers, float* __restrict__ out)
{
    const int b   = blockIdx.x >> 6;
    const int k   = blockIdx.x & 63;
    const int tid = threadIdx.x;

    const float wsum = wsumbuf[b * K_ + k];

    const float* vp = vlad_part + ((size_t)(b * 16) * K_ + k) * D_;
    float a0 = 0.f, a1 = 0.f;
    #pragma unroll 4
    for (int gg = 0; gg < 16; ++gg) {
        a0 += vp[(size_t)gg * K_ * D_ + tid];
        a1 += vp[(size_t)gg * K_ * D_ + tid + 256];
    }
    const float* cr = centers + k * D_;
    const float v0 = a0 - wsum * cr[tid];
    const float v1 = a1 - wsum * cr[tid + 256];

    float ss = v0 * v0 + v1 * v1;
    __shared__ float red2[4];
    #pragma unroll
    for (int off = 32; off > 0; off >>= 1) ss += __shfl_down(ss, off, 64);
    if ((tid & 63) == 0) red2[tid >> 6] = ss;
    __syncthreads();
    const float nrm = sqrtf(red2[0] + red2[1] + red2[2] + red2[3]);
    const float scale = 1.0f / (8.0f * fmaxf(nrm, 1e-12f));

    float* outr = out + ((size_t)b * K_ + k) * D_;
    outr[tid]       = v0 * scale;
    outr[tid + 256] = v1 * scale;
}

extern "C" void kernel_launch(void* const* d_in, const int* in_sizes, int n_in,
                              void* d_out, int out_size, void* d_ws, size_t ws_size,
                              hipStream_t stream) {
    const float* x       = (const float*)d_in[0];
    const float* conv_w  = (const float*)d_in[1];
    const float* conv_b  = (const float*)d_in[2];
    const float* centers = (const float*)d_in[3];
    float* out = (float*)d_out;

    char* wsp = (char*)d_ws;
    float* vlad_part    = (float*)wsp;                               // 32 MiB
    float* wsumbuf      = (float*)(wsp + (32u << 20));               // 4 KiB
    unsigned short* cwL = (unsigned short*)(wsp + (32u << 20) + (1u << 16)); // 192 KiB

    hipMemsetAsync(wsumbuf, 0, B_ * K_ * sizeof(float), stream);

    static bool attr_set = false;
    if (!attr_set) {   // allow 156 KB dynamic LDS (gfx950 WG max = 160 KiB)
        (void)hipFuncSetAttribute((const void*)k_fused,
                                  hipFuncAttributeMaxDynamicSharedMemorySize, 159744);
        attr_set = true;
    }

    k_prep<<<32, 256, 0, stream>>>(conv_w, cwL);
    k_fused<<<B_ * 16, 512, 159744, stream>>>(x, cwL, conv_b, vlad_part, wsumbuf);
    k_norm<<<B_ * K_, 256, 0, stream>>>(wsumbuf, vlad_part, centers, out);
}

// Round 5
// 297.464 us; speedup vs baseline: 1.1848x; 1.0343x over previous
//
#include <hip/hip_runtime.h>
#include <hip/hip_bf16.h>
#include <math.h>

#define B_ 16
#define D_ 512
#define N_ 4096   // H*W
#define K_ 64

typedef __attribute__((ext_vector_type(8))) short bfrag;   // 8 bf16 = 4 VGPRs
typedef __attribute__((ext_vector_type(4))) float f32x4;

static __device__ __forceinline__ float bf2f(unsigned short u) {
    return __uint_as_float(((unsigned)u) << 16);
}
static __device__ __forceinline__ unsigned short f2bf(float v) {
    __hip_bfloat16 h = __float2bfloat16(v);   // RNE
    union { __hip_bfloat16 h; unsigned short u; } cv; cv.h = h; return cv.u;
}
static __device__ __forceinline__ void split3(float v, unsigned short& h,
                                              unsigned short& m, unsigned short& l) {
    h = f2bf(v); float r1 = v - bf2f(h);
    m = f2bf(r1); float r2 = r1 - bf2f(m);
    l = f2bf(r2);
}
static __device__ __forceinline__ void split2(float v, unsigned short& h,
                                              unsigned short& l) {
    h = f2bf(v); l = f2bf(v - bf2f(h));
}
#define MFMA(a, b, c) __builtin_amdgcn_mfma_f32_16x16x32_bf16((a), (b), (c), 0, 0, 0)

// w-limb plane [64 k][72]: 8-short chunks rotated by k -> phase-C bfrag reads
// (16 c-lanes = 16 k-rows, same n-chunk) land 2-way max. Proven in the 112us run.
static __device__ __forceinline__ int ws2_idx(int k, int n) {
    const int CH  = n >> 3;
    const int CHs = (CH - 2 * (k & 7)) & 7;
    return k * 72 + CHs * 8 + (n & 7);
}

// ---------------------------------------------------------------------------
// K0: pre-split conv_w into 3 bf16 limb planes [lv][64][512] (192 KB total).
// ---------------------------------------------------------------------------
__global__ __launch_bounds__(256) void k_prep(
    const float* __restrict__ conv_w, unsigned short* __restrict__ cwL)
{
    const int i = blockIdx.x * 256 + threadIdx.x;
    const float4 v = *(const float4*)&conv_w[i * 4];
    const float vv[4] = {v.x, v.y, v.z, v.w};
    unsigned short h[4], m[4], l[4];
    #pragma unroll
    for (int j = 0; j < 4; ++j) split3(vv[j], h[j], m[j], l[j]);
    *(ushort4*)&cwL[0 * (K_ * D_) + i * 4] = make_ushort4(h[0], h[1], h[2], h[3]);
    *(ushort4*)&cwL[1 * (K_ * D_) + i * 4] = make_ushort4(m[0], m[1], m[2], m[3]);
    *(ushort4*)&cwL[2 * (K_ * D_) + i * 4] = make_ushort4(l[0], l[1], l[2], l[3]);
}

// ---------------------------------------------------------------------------
// F4: fused logits+softmax+wsum+wx with SMALL LDS (39 KB) -> 2 blocks/CU.
// Grid 512 = B x 32 n-groups of 128, 512 threads = 8 waves.
// Phase A (= baseline K1 staging verbatim, 8 waves): per 32-d step stage
//   3-limb x into xs[3][128][40] (chunk-swizzled), 24 MFMA/wave. cw frags
//   straight from global (L2-hot).
// Phase B: cross-wave softmax (redm/reds[2][128]); w limbs -> LDS planes
//   (ws2_idx swizzle), fused wsum.
// Phase C: barrier-free; x RE-READ from global f32 (tile is L2-resident from
//   phase A), split2 on the fly; w frags from LDS; acc2 16k x 256d per wave;
//   coalesced partial store (no atomics). Cross-block overlap (2 blocks/CU)
//   hides the phase-A barrier drains -- the mechanism the 1-block/CU variants
//   lacked.
// ---------------------------------------------------------------------------
__global__ __launch_bounds__(512, 4) void k_fused(
    const float* __restrict__ x, const unsigned short* __restrict__ cwL,
    const float* __restrict__ conv_b, float* __restrict__ vlad_part,
    float* __restrict__ wsumbuf)
{
    const int b    = blockIdx.x >> 5;
    const int g    = blockIdx.x & 31;          // n-group: n in [g*128, g*128+128)
    const int tid  = threadIdx.x;
    const int w    = tid >> 6;
    const int lane = tid & 63;
    const int q    = lane >> 4;
    const int c    = lane & 15;
    const int ktb  = (w & 1) * 32;             // phase A: k-half
    const int ntb  = (w >> 1) * 32;            // phase A: n-quarter
    const int kw   = w >> 1;                   // phase C: 16-k quarter
    const int nw   = w & 1;                    // phase C: d interleave half

    __shared__ union {
        unsigned short xs[3][128][40];         // 30,720 B (phase A)
        unsigned short ws[2][2][64 * 72];      // 36,864 B [n-half][limb][k*72]
    } u;
    __shared__ float redm[2][128];
    __shared__ float reds[2][128];

    const float* xb = x + (size_t)b * (D_ * N_) + g * 128;

    f32x4 acc[2][2];
    #pragma unroll
    for (int kt = 0; kt < 2; ++kt)
        #pragma unroll
        for (int nt = 0; nt < 2; ++nt) acc[kt][nt] = (f32x4){0.f, 0.f, 0.f, 0.f};

    // ---- phase A: logits via 3-way-split bf16 MFMA (baseline-K1 pattern)
    #pragma unroll 1
    for (int d0 = 0; d0 < D_; d0 += 32) {
        bfrag af[2][3];
        #pragma unroll
        for (int kt = 0; kt < 2; ++kt)
            #pragma unroll
            for (int lv = 0; lv < 3; ++lv)
                af[kt][lv] = *(const bfrag*)(cwL + lv * (K_ * D_)
                                             + (ktb + kt * 16 + c) * D_ + d0 + q * 8);
        #pragma unroll
        for (int i = 0; i < 2; ++i) {
            const int s   = i * 512 + tid;
            const int xn  = s & 127;
            const int j   = s >> 7;                       // 8B chunk 0..7
            const int Cs  = ((j >> 1) ^ ((xn >> 3) & 3)); // swizzled 16B chunk
            const int dsw = (Cs * 2 + (j & 1)) * 4;
            unsigned short h4[4], m4[4], l4[4];
            #pragma unroll
            for (int r = 0; r < 4; ++r) {
                const float v = xb[(size_t)(d0 + j * 4 + r) * N_ + xn];
                split3(v, h4[r], m4[r], l4[r]);
            }
            *(ushort4*)&u.xs[0][xn][dsw] = make_ushort4(h4[0], h4[1], h4[2], h4[3]);
            *(ushort4*)&u.xs[1][xn][dsw] = make_ushort4(m4[0], m4[1], m4[2], m4[3]);
            *(ushort4*)&u.xs[2][xn][dsw] = make_ushort4(l4[0], l4[1], l4[2], l4[3]);
        }
        __syncthreads();
        #pragma unroll
        for (int nt = 0; nt < 2; ++nt) {
            const int row = ntb + nt * 16 + c;
            const int qs  = (q ^ ((row >> 3) & 3)) * 8;
            const bfrag bf0 = *(const bfrag*)&u.xs[0][row][qs];
            const bfrag bf1 = *(const bfrag*)&u.xs[1][row][qs];
            const bfrag bf2 = *(const bfrag*)&u.xs[2][row][qs];
            #pragma unroll
            for (int kt = 0; kt < 2; ++kt) {
                f32x4 a = acc[kt][nt];
                a = MFMA(af[kt][0], bf0, a);   // hh
                a = MFMA(af[kt][0], bf1, a);   // hm
                a = MFMA(af[kt][1], bf0, a);   // mh
                a = MFMA(af[kt][1], bf1, a);   // mm
                a = MFMA(af[kt][0], bf2, a);   // hl
                a = MFMA(af[kt][2], bf0, a);   // lh
                acc[kt][nt] = a;
            }
        }
        __syncthreads();
    }

    // ---- phase B: bias + cross-wave softmax + w limbs to LDS + fused wsum
    #pragma unroll
    for (int kt = 0; kt < 2; ++kt)
        #pragma unroll
        for (int r = 0; r < 4; ++r) {
            const float bias = conv_b[ktb + kt * 16 + q * 4 + r];
            #pragma unroll
            for (int nt = 0; nt < 2; ++nt) acc[kt][nt][r] += bias;
        }

    float mloc[2];
    #pragma unroll
    for (int nt = 0; nt < 2; ++nt) {
        float m = acc[0][nt][0];
        #pragma unroll
        for (int kt = 0; kt < 2; ++kt)
            #pragma unroll
            for (int r = 0; r < 4; ++r) m = fmaxf(m, acc[kt][nt][r]);
        m = fmaxf(m, __shfl_xor(m, 16));
        m = fmaxf(m, __shfl_xor(m, 32));
        mloc[nt] = m;
    }
    if (q == 0)
        #pragma unroll
        for (int nt = 0; nt < 2; ++nt) redm[w & 1][ntb + nt * 16 + c] = mloc[nt];
    __syncthreads();
    float mall[2];
    #pragma unroll
    for (int nt = 0; nt < 2; ++nt) {
        const int n = ntb + nt * 16 + c;
        mall[nt] = fmaxf(redm[0][n], redm[1][n]);
    }
    float sloc[2] = {0.f, 0.f};
    #pragma unroll
    for (int nt = 0; nt < 2; ++nt) {
        #pragma unroll
        for (int kt = 0; kt < 2; ++kt)
            #pragma unroll
            for (int r = 0; r < 4; ++r) {
                const float e = __expf(acc[kt][nt][r] - mall[nt]);
                acc[kt][nt][r] = e;
                sloc[nt] += e;
            }
        sloc[nt] += __shfl_xor(sloc[nt], 16);
        sloc[nt] += __shfl_xor(sloc[nt], 32);
    }
    if (q == 0)
        #pragma unroll
        for (int nt = 0; nt < 2; ++nt) reds[w & 1][ntb + nt * 16 + c] = sloc[nt];
    __syncthreads();

    float wacc[2][4] = {{0.f, 0.f, 0.f, 0.f}, {0.f, 0.f, 0.f, 0.f}};
    #pragma unroll
    for (int nt = 0; nt < 2; ++nt) {
        const int n = ntb + nt * 16 + c;
        const float inv = 1.0f / (reds[0][n] + reds[1][n]);
        #pragma unroll
        for (int kt = 0; kt < 2; ++kt)
            #pragma unroll
            for (int r = 0; r < 4; ++r) {
                const float v = acc[kt][nt][r] * inv;
                unsigned short hi, lo;
                split2(v, hi, lo);
                const int k = ktb + kt * 16 + q * 4 + r;
                u.ws[n >> 6][0][ws2_idx(k, n & 63)] = hi;   // xs dead (2 barriers ago)
                u.ws[n >> 6][1][ws2_idx(k, n & 63)] = lo;
                wacc[kt][r] += v;
            }
    }
    // fused wsum: reduce over 16 c-lanes, one atomic per (k, wave)
    #pragma unroll
    for (int msk = 1; msk < 16; msk <<= 1)
        #pragma unroll
        for (int kt = 0; kt < 2; ++kt)
            #pragma unroll
            for (int r = 0; r < 4; ++r)
                wacc[kt][r] += __shfl_xor(wacc[kt][r], msk);
    if (c == 0)
        #pragma unroll
        for (int kt = 0; kt < 2; ++kt)
            #pragma unroll
            for (int r = 0; r < 4; ++r)
                atomicAdd(&wsumbuf[b * K_ + ktb + kt * 16 + q * 4 + r], wacc[kt][r]);
    __syncthreads();   // ws visible to all waves

    // ---- phase C: wx += w . x^T; x re-read from global (L2-hot), no barriers
    f32x4 acc2[16];
    #pragma unroll
    for (int i = 0; i < 16; ++i) acc2[i] = (f32x4){0.f, 0.f, 0.f, 0.f};

    #pragma unroll 1
    for (int ns = 0; ns < 4; ++ns) {
        const int no = (ns & 1) * 32 + q * 8;
        const bfrag awh = *(const bfrag*)&u.ws[ns >> 1][0][ws2_idx(kw * 16 + c, no)];
        const bfrag awl = *(const bfrag*)&u.ws[ns >> 1][1][ws2_idx(kw * 16 + c, no)];
        #pragma unroll
        for (int i = 0; i < 16; ++i) {
            const int row = i * 32 + nw * 16 + c;   // d-row
            const float4 v0 = *(const float4*)&xb[(size_t)row * N_ + ns * 32 + q * 8];
            const float4 v1 = *(const float4*)&xb[(size_t)row * N_ + ns * 32 + q * 8 + 4];
            const float vv[8] = {v0.x, v0.y, v0.z, v0.w, v1.x, v1.y, v1.z, v1.w};
            bfrag bh, bl;
            #pragma unroll
            for (int j = 0; j < 8; ++j) {
                unsigned short hh, ll;
                split2(vv[j], hh, ll);
                bh[j] = (short)hh;
                bl[j] = (short)ll;
            }
            f32x4 a = acc2[i];
            a = MFMA(awh, bh, a);
            a = MFMA(awh, bl, a);
            a = MFMA(awl, bh, a);
            acc2[i] = a;
        }
    }

    // ---- partial store (coalesced along d, no atomics)
    float* vp = vlad_part + ((size_t)(b * 32 + g) * K_) * D_;
    #pragma unroll
    for (int i = 0; i < 16; ++i)
        #pragma unroll
        for (int r = 0; r < 4; ++r)
            vp[(size_t)(kw * 16 + q * 4 + r) * D_ + i * 32 + nw * 16 + c] = acc2[i][r];
}

// ---------------------------------------------------------------------------
// K3: reduce 32 n-group partials; v = vlad - wsum*c; row L2; global /8.
// ---------------------------------------------------------------------------
__global__ __launch_bounds__(256) void k_norm(
    const float* __restrict__ wsumbuf, const float* __restrict__ vlad_part,
    const float* __restrict__ centers, float* __restrict__ out)
{
    const int b   = blockIdx.x >> 6;
    const int k   = blockIdx.x & 63;
    const int tid = threadIdx.x;

    const float wsum = wsumbuf[b * K_ + k];

    const float* vp = vlad_part + ((size_t)(b * 32) * K_ + k) * D_;
    float a0 = 0.f, a1 = 0.f;
    #pragma unroll 4
    for (int gg = 0; gg < 32; ++gg) {
        a0 += vp[(size_t)gg * K_ * D_ + tid];
        a1 += vp[(size_t)gg * K_ * D_ + tid + 256];
    }
    const float* cr = centers + k * D_;
    const float v0 = a0 - wsum * cr[tid];
    const float v1 = a1 - wsum * cr[tid + 256];

    float ss = v0 * v0 + v1 * v1;
    __shared__ float red2[4];
    #pragma unroll
    for (int off = 32; off > 0; off >>= 1) ss += __shfl_down(ss, off, 64);
    if ((tid & 63) == 0) red2[tid >> 6] = ss;
    __syncthreads();
    const float nrm = sqrtf(red2[0] + red2[1] + red2[2] + red2[3]);
    const float scale = 1.0f / (8.0f * fmaxf(nrm, 1e-12f));

    float* outr = out + ((size_t)b * K_ + k) * D_;
    outr[tid]       = v0 * scale;
    outr[tid + 256] = v1 * scale;
}

extern "C" void kernel_launch(void* const* d_in, const int* in_sizes, int n_in,
                              void* d_out, int out_size, void* d_ws, size_t ws_size,
                              hipStream_t stream) {
    const float* x       = (const float*)d_in[0];
    const float* conv_w  = (const float*)d_in[1];
    const float* conv_b  = (const float*)d_in[2];
    const float* centers = (const float*)d_in[3];
    float* out = (float*)d_out;

    char* wsp = (char*)d_ws;
    float* vlad_part    = (float*)wsp;                               // 64 MiB
    float* wsumbuf      = (float*)(wsp + (64u << 20));               // 4 KiB
    unsigned short* cwL = (unsigned short*)(wsp + (64u << 20) + (1u << 16)); // 192 KiB

    hipMemsetAsync(wsumbuf, 0, B_ * K_ * sizeof(float), stream);

    k_prep<<<32, 256, 0, stream>>>(conv_w, cwL);
    k_fused<<<B_ * 32, 512, 0, stream>>>(x, cwL, conv_b, vlad_part, wsumbuf);
    k_norm<<<B_ * K_, 256, 0, stream>>>(wsumbuf, vlad_part, centers, out);
}

// Round 7
// 256.893 us; speedup vs baseline: 1.3719x; 1.1579x over previous
//
#include <hip/hip_runtime.h>
#include <hip/hip_bf16.h>
#include <math.h>

#define B_ 16
#define D_ 512
#define N_ 4096   // H*W
#define K_ 64

typedef __attribute__((ext_vector_type(8))) short bfrag;   // 8 bf16 = 4 VGPRs
typedef __attribute__((ext_vector_type(4))) float f32x4;

static __device__ __forceinline__ float bf2f(unsigned short u) {
    return __uint_as_float(((unsigned)u) << 16);
}
static __device__ __forceinline__ unsigned short f2bf(float v) {
    __hip_bfloat16 h = __float2bfloat16(v);   // RNE
    union { __hip_bfloat16 h; unsigned short u; } cv; cv.h = h; return cv.u;
}
static __device__ __forceinline__ void split3(float v, unsigned short& h,
                                              unsigned short& m, unsigned short& l) {
    h = f2bf(v); float r1 = v - bf2f(h);
    m = f2bf(r1); float r2 = r1 - bf2f(m);
    l = f2bf(r2);
}
static __device__ __forceinline__ void split2(float v, unsigned short& h,
                                              unsigned short& l) {
    h = f2bf(v); l = f2bf(v - bf2f(h));
}
#define MFMA(a, b, c) __builtin_amdgcn_mfma_f32_16x16x32_bf16((a), (b), (c), 0, 0, 0)

// ---------------------------------------------------------------------------
// K0: pre-split conv_w into 3 bf16 limb planes [lv][64][512] (192 KB total).
// ---------------------------------------------------------------------------
__global__ __launch_bounds__(256) void k_prep(
    const float* __restrict__ conv_w, unsigned short* __restrict__ cwL)
{
    const int i = blockIdx.x * 256 + threadIdx.x;
    const float4 v = *(const float4*)&conv_w[i * 4];
    const float vv[4] = {v.x, v.y, v.z, v.w};
    unsigned short h[4], m[4], l[4];
    #pragma unroll
    for (int j = 0; j < 4; ++j) split3(vv[j], h[j], m[j], l[j]);
    *(ushort4*)&cwL[0 * (K_ * D_) + i * 4] = make_ushort4(h[0], h[1], h[2], h[3]);
    *(ushort4*)&cwL[1 * (K_ * D_) + i * 4] = make_ushort4(m[0], m[1], m[2], m[3]);
    *(ushort4*)&cwL[2 * (K_ * D_) + i * 4] = make_ushort4(l[0], l[1], l[2], l[3]);
}

// ---------------------------------------------------------------------------
// K1: logits via 3-way-split bf16 MFMA + softmax + w limbs + fused wsum.
// Baseline r3 geometry (128n tile, grid 512). Deltas vs the 237us baseline:
//  (a) cw fragments read DIRECTLY from global cwL (L2-hot, pattern proven in
//      the fused phase-A) -> no cws LDS stage -> LDS 48->32 KB -> 5 blocks/CU
//      (launch_bounds(256,5) caps VGPR at 102; baseline measured 88).
//  (b) w limbs stored interleaved as one uint (hi | lo<<16): one 4B store per
//      element instead of two 2B stores. K2 de-interleaves at staging; the
//      LDS image and all arithmetic are bit-identical to baseline.
// ---------------------------------------------------------------------------
__global__ __launch_bounds__(256, 5) void k_logits_softmax(
    const float* __restrict__ x, const unsigned short* __restrict__ cwL,
    const float* __restrict__ conv_b,
    unsigned int* __restrict__ whl, float* __restrict__ wsumbuf)
{
    const int b   = blockIdx.x >> 5;
    const int n0  = (blockIdx.x & 31) * 128;
    const int tid  = threadIdx.x;
    const int w    = tid >> 6;
    const int lane = tid & 63;
    const int q = lane >> 4;
    const int c = lane & 15;
    const int ktb = (w & 1) * 32;
    const int ntb = (w >> 1) * 64;

    __shared__ unsigned short xs[3][128][40];   // [lvl][n][d-swizzled]
    __shared__ float redm[2][128];
    __shared__ float reds[2][128];

    f32x4 acc[2][4];
    #pragma unroll
    for (int kt = 0; kt < 2; ++kt)
        #pragma unroll
        for (int nt = 0; nt < 4; ++nt) acc[kt][nt] = (f32x4){0.f, 0.f, 0.f, 0.f};

    const float* xb = x + (size_t)b * D_ * N_ + n0;
    const unsigned short* cwp = cwL + (ktb + c) * D_ + q * 8;

    for (int d0 = 0; d0 < D_; d0 += 32) {
        // cw frags straight from global (L2-hot); issued before staging so the
        // latency hides under the x-stage.
        bfrag af[2][3];
        #pragma unroll
        for (int kt = 0; kt < 2; ++kt)
            #pragma unroll
            for (int lv = 0; lv < 3; ++lv)
                af[kt][lv] = *(const bfrag*)(cwp + lv * (K_ * D_) + kt * 16 * D_ + d0);
        // stage x 32d x 128n transposed -> xs[n][d], split3, swizzled chunks
        #pragma unroll
        for (int i = 0; i < 4; ++i) {
            const int s  = i * 256 + tid;
            const int xn = s & 127;
            const int j  = s >> 7;                      // 8B chunk 0..7
            const int Cs = ((j >> 1) ^ ((xn >> 3) & 3)); // swizzled 16B chunk
            const int dsw = (Cs * 2 + (j & 1)) * 4;      // swizzled short offset
            const int dg4 = j * 4;                       // source d offset
            unsigned short h[4], m[4], l[4];
            #pragma unroll
            for (int r = 0; r < 4; ++r) {
                const float v = xb[(size_t)(d0 + dg4 + r) * N_ + xn];
                split3(v, h[r], m[r], l[r]);
            }
            *(ushort4*)&xs[0][xn][dsw] = make_ushort4(h[0], h[1], h[2], h[3]);
            *(ushort4*)&xs[1][xn][dsw] = make_ushort4(m[0], m[1], m[2], m[3]);
            *(ushort4*)&xs[2][xn][dsw] = make_ushort4(l[0], l[1], l[2], l[3]);
        }
        __syncthreads();

        #pragma unroll
        for (int nt = 0; nt < 4; ++nt) {
            const int row = ntb + nt * 16 + c;
            const int qs  = (q ^ ((row >> 3) & 3)) * 8;  // swizzled read chunk
            bfrag bf[3];
            #pragma unroll
            for (int lv = 0; lv < 3; ++lv)
                bf[lv] = *(const bfrag*)&xs[lv][row][qs];
            #pragma unroll
            for (int kt = 0; kt < 2; ++kt) {
                f32x4 a = acc[kt][nt];
                a = MFMA(af[kt][0], bf[0], a);   // hh
                a = MFMA(af[kt][0], bf[1], a);   // hm
                a = MFMA(af[kt][1], bf[0], a);   // mh
                a = MFMA(af[kt][1], bf[1], a);   // mm
                a = MFMA(af[kt][0], bf[2], a);   // hl
                a = MFMA(af[kt][2], bf[0], a);   // lh
                acc[kt][nt] = a;
            }
        }
        __syncthreads();
    }

    // ---- bias + cross-wave softmax (lane owns k=ktb+kt*16+q*4+r, n=ntb+nt*16+c)
    #pragma unroll
    for (int kt = 0; kt < 2; ++kt)
        #pragma unroll
        for (int r = 0; r < 4; ++r) {
            const float bias = conv_b[ktb + kt * 16 + q * 4 + r];
            #pragma unroll
            for (int nt = 0; nt < 4; ++nt) acc[kt][nt][r] += bias;
        }

    float mloc[4];
    #pragma unroll
    for (int nt = 0; nt < 4; ++nt) {
        float m = acc[0][nt][0];
        #pragma unroll
        for (int kt = 0; kt < 2; ++kt)
            #pragma unroll
            for (int r = 0; r < 4; ++r) m = fmaxf(m, acc[kt][nt][r]);
        m = fmaxf(m, __shfl_xor(m, 16));
        m = fmaxf(m, __shfl_xor(m, 32));
        mloc[nt] = m;
    }
    if (q == 0)
        #pragma unroll
        for (int nt = 0; nt < 4; ++nt) redm[w & 1][ntb + nt * 16 + c] = mloc[nt];
    __syncthreads();
    float mall[4];
    #pragma unroll
    for (int nt = 0; nt < 4; ++nt)
        mall[nt] = fmaxf(redm[0][ntb + nt * 16 + c], redm[1][ntb + nt * 16 + c]);

    float sloc[4] = {0.f, 0.f, 0.f, 0.f};
    #pragma unroll
    for (int nt = 0; nt < 4; ++nt) {
        #pragma unroll
        for (int kt = 0; kt < 2; ++kt)
            #pragma unroll
            for (int r = 0; r < 4; ++r) {
                const float e = __expf(acc[kt][nt][r] - mall[nt]);
                acc[kt][nt][r] = e;
                sloc[nt] += e;
            }
        sloc[nt] += __shfl_xor(sloc[nt], 16);
        sloc[nt] += __shfl_xor(sloc[nt], 32);
    }
    if (q == 0)
        #pragma unroll
        for (int nt = 0; nt < 4; ++nt) reds[w & 1][ntb + nt * 16 + c] = sloc[nt];
    __syncthreads();

    float wacc[2][4] = {{0.f, 0.f, 0.f, 0.f}, {0.f, 0.f, 0.f, 0.f}};
    #pragma unroll
    for (int nt = 0; nt < 4; ++nt) {
        const float inv = 1.0f / (reds[0][ntb + nt * 16 + c] + reds[1][ntb + nt * 16 + c]);
        #pragma unroll
        for (int kt = 0; kt < 2; ++kt)
            #pragma unroll
            for (int r = 0; r < 4; ++r) {
                const float v = acc[kt][nt][r] * inv;
                unsigned short hi, lo;
                split2(v, hi, lo);
                const size_t idx = ((size_t)b * K_ + ktb + kt * 16 + q * 4 + r) * N_
                                 + n0 + ntb + nt * 16 + c;
                whl[idx] = (unsigned)hi | ((unsigned)lo << 16);
                wacc[kt][r] += v;
            }
    }
    // fused wsum: reduce over the 16 c-lanes, then one atomic per (k, wave)
    #pragma unroll
    for (int msk = 1; msk < 16; msk <<= 1)
        #pragma unroll
        for (int kt = 0; kt < 2; ++kt)
            #pragma unroll
            for (int r = 0; r < 4; ++r)
                wacc[kt][r] += __shfl_xor(wacc[kt][r], msk);
    if (c == 0)
        #pragma unroll
        for (int kt = 0; kt < 2; ++kt)
            #pragma unroll
            for (int r = 0; r < 4; ++r)
                atomicAdd(&wsumbuf[b * K_ + ktb + kt * 16 + q * 4 + r], wacc[kt][r]);
}

// ---------------------------------------------------------------------------
// K2: vlad += w . x^T via 2-way-split bf16 MFMA. Baseline r3 geometry (nc=8,
// grid 512 — best measured). Deltas: interleaved whl plane (de-interleave at
// staging; LDS image identical to baseline), launch_bounds(256,5) so the
// 30.7 KB LDS actually yields 5 blocks/CU (VGPR cap 102).
// ---------------------------------------------------------------------------
__global__ __launch_bounds__(256, 5) void k_wx(
    const float* __restrict__ x, const unsigned int* __restrict__ whl,
    float* __restrict__ vlad)
{
    const int nc = blockIdx.x & 7;
    const int dc = (blockIdx.x >> 3) & 3;
    const int b  = blockIdx.x >> 5;
    const int tid  = threadIdx.x;
    const int w    = tid >> 6;
    const int lane = tid & 63;
    const int q = lane >> 4;
    const int c = lane & 15;
    const int ktb = (w & 1) * 32;
    const int dtb = (w >> 1) * 64;

    __shared__ unsigned short ws2[2][64][40];    // [lvl][k][n]
    __shared__ unsigned short xs2[2][128][40];   // [lvl][d][n]

    f32x4 acc[2][4];
    #pragma unroll
    for (int kt = 0; kt < 2; ++kt)
        #pragma unroll
        for (int dt = 0; dt < 4; ++dt) acc[kt][dt] = (f32x4){0.f, 0.f, 0.f, 0.f};

    const float* xb = x + (size_t)b * D_ * N_ + (size_t)dc * 128 * N_;
    const unsigned int* wb = whl + (size_t)b * K_ * N_;

    const int wk = tid >> 2;            // w row
    const int wn = (tid & 3) * 8;       // w n-offset
    const int xd = tid >> 3;            // x row (i adds 32i)
    const int xn = (tid & 7) * 4;       // x n-offset

    const int nbase = nc * 512;
    for (int n0 = nbase; n0 < nbase + 512; n0 += 32) {
        {
            const uint4 a = *(const uint4*)&wb[(size_t)wk * N_ + n0 + wn];
            const uint4 bq = *(const uint4*)&wb[(size_t)wk * N_ + n0 + wn + 4];
            bfrag h8, l8;
            h8[0] = (short)(unsigned short)a.x;  l8[0] = (short)(unsigned short)(a.x >> 16);
            h8[1] = (short)(unsigned short)a.y;  l8[1] = (short)(unsigned short)(a.y >> 16);
            h8[2] = (short)(unsigned short)a.z;  l8[2] = (short)(unsigned short)(a.z >> 16);
            h8[3] = (short)(unsigned short)a.w;  l8[3] = (short)(unsigned short)(a.w >> 16);
            h8[4] = (short)(unsigned short)bq.x; l8[4] = (short)(unsigned short)(bq.x >> 16);
            h8[5] = (short)(unsigned short)bq.y; l8[5] = (short)(unsigned short)(bq.y >> 16);
            h8[6] = (short)(unsigned short)bq.z; l8[6] = (short)(unsigned short)(bq.z >> 16);
            h8[7] = (short)(unsigned short)bq.w; l8[7] = (short)(unsigned short)(bq.w >> 16);
            *(bfrag*)&ws2[0][wk][wn] = h8;
            *(bfrag*)&ws2[1][wk][wn] = l8;
        }
        #pragma unroll
        for (int i = 0; i < 4; ++i) {
            const float4 v = *(const float4*)&xb[(size_t)(i * 32 + xd) * N_ + n0 + xn];
            const float vv[4] = {v.x, v.y, v.z, v.w};
            unsigned short h[4], l[4];
            #pragma unroll
            for (int j = 0; j < 4; ++j) split2(vv[j], h[j], l[j]);
            *(ushort4*)&xs2[0][i * 32 + xd][xn] = make_ushort4(h[0], h[1], h[2], h[3]);
            *(ushort4*)&xs2[1][i * 32 + xd][xn] = make_ushort4(l[0], l[1], l[2], l[3]);
        }
        __syncthreads();

        bfrag afh[2], afl[2];
        #pragma unroll
        for (int kt = 0; kt < 2; ++kt) {
            afh[kt] = *(const bfrag*)&ws2[0][ktb + kt * 16 + c][q * 8];
            afl[kt] = *(const bfrag*)&ws2[1][ktb + kt * 16 + c][q * 8];
        }
        #pragma unroll
        for (int dt = 0; dt < 4; ++dt) {
            const bfrag bh = *(const bfrag*)&xs2[0][dtb + dt * 16 + c][q * 8];
            const bfrag bl = *(const bfrag*)&xs2[1][dtb + dt * 16 + c][q * 8];
            #pragma unroll
            for (int kt = 0; kt < 2; ++kt) {
                f32x4 a = acc[kt][dt];
                a = MFMA(afh[kt], bh, a);
                a = MFMA(afh[kt], bl, a);
                a = MFMA(afl[kt], bh, a);
                acc[kt][dt] = a;
            }
        }
        __syncthreads();
    }

    #pragma unroll
    for (int kt = 0; kt < 2; ++kt)
        #pragma unroll
        for (int dt = 0; dt < 4; ++dt)
            #pragma unroll
            for (int r = 0; r < 4; ++r) {
                const int k = ktb + kt * 16 + q * 4 + r;
                const int d = dc * 128 + dtb + dt * 16 + c;
                atomicAdd(&vlad[((size_t)b * K_ + k) * D_ + d], acc[kt][dt][r]);
            }
}

// ---------------------------------------------------------------------------
// K3: v = vlad - wsum*c; row L2-norm; global norm = /8.  (wsum precomputed)
// ---------------------------------------------------------------------------
__global__ __launch_bounds__(256) void k_norm(
    const float* __restrict__ wsumbuf, const float* __restrict__ vlad,
    const float* __restrict__ centers, float* __restrict__ out)
{
    const int b = blockIdx.x >> 6;
    const int k = blockIdx.x & 63;
    const int tid = threadIdx.x;

    const float wsum = wsumbuf[b * K_ + k];

    const float* vr = vlad + ((size_t)b * K_ + k) * D_;
    const float* cr = centers + k * D_;
    const float v0 = vr[tid]       - wsum * cr[tid];
    const float v1 = vr[tid + 256] - wsum * cr[tid + 256];

    float ss = v0 * v0 + v1 * v1;
    __shared__ float red2[4];
    #pragma unroll
    for (int off = 32; off > 0; off >>= 1) ss += __shfl_down(ss, off, 64);
    if ((tid & 63) == 0) red2[tid >> 6] = ss;
    __syncthreads();
    const float nrm = sqrtf(red2[0] + red2[1] + red2[2] + red2[3]);
    const float scale = 1.0f / (8.0f * fmaxf(nrm, 1e-12f));

    float* outr = out + ((size_t)b * K_ + k) * D_;
    outr[tid]       = v0 * scale;
    outr[tid + 256] = v1 * scale;
}

extern "C" void kernel_launch(void* const* d_in, const int* in_sizes, int n_in,
                              void* d_out, int out_size, void* d_ws, size_t ws_size,
                              hipStream_t stream) {
    const float* x       = (const float*)d_in[0];
    const float* conv_w  = (const float*)d_in[1];
    const float* conv_b  = (const float*)d_in[2];
    const float* centers = (const float*)d_in[3];
    float* out = (float*)d_out;

    char* wsb = (char*)d_ws;
    float* vlad         = (float*)wsb;                          // 2 MiB
    float* wsumbuf      = (float*)(wsb + (2u << 20));           // 4 KiB
    unsigned int* whl   = (unsigned int*)(wsb + (3u << 20));    // 16 MiB
    unsigned short* cwL = (unsigned short*)(wsb + (20u << 20)); // 192 KiB

    hipMemsetAsync(vlad, 0, (2u << 20) + 4096, stream);

    k_prep<<<32, 256, 0, stream>>>(conv_w, cwL);
    k_logits_softmax<<<B_ * 32, 256, 0, stream>>>(x, cwL, conv_b, whl, wsumbuf);
    k_wx<<<B_ * 4 * 8, 256, 0, stream>>>(x, whl, vlad);
    k_norm<<<B_ * K_, 256, 0, stream>>>(wsumbuf, vlad, centers, out);
}

// Round 8
// 237.975 us; speedup vs baseline: 1.4810x; 1.0795x over previous
//
#include <hip/hip_runtime.h>
#include <hip/hip_bf16.h>
#include <math.h>

#define B_ 16
#define D_ 512
#define N_ 4096   // H*W
#define K_ 64

typedef __attribute__((ext_vector_type(8))) short bfrag;   // 8 bf16 = 4 VGPRs
typedef __attribute__((ext_vector_type(4))) float f32x4;

static __device__ __forceinline__ float bf2f(unsigned short u) {
    return __uint_as_float(((unsigned)u) << 16);
}
static __device__ __forceinline__ unsigned short f2bf(float v) {
    __hip_bfloat16 h = __float2bfloat16(v);   // RNE
    union { __hip_bfloat16 h; unsigned short u; } cv; cv.h = h; return cv.u;
}
static __device__ __forceinline__ void split3(float v, unsigned short& h,
                                              unsigned short& m, unsigned short& l) {
    h = f2bf(v); float r1 = v - bf2f(h);
    m = f2bf(r1); float r2 = r1 - bf2f(m);
    l = f2bf(r2);
}
static __device__ __forceinline__ void split2(float v, unsigned short& h,
                                              unsigned short& l) {
    h = f2bf(v); l = f2bf(v - bf2f(h));
}
#define MFMA(a, b, c) __builtin_amdgcn_mfma_f32_16x16x32_bf16((a), (b), (c), 0, 0, 0)

// ---------------------------------------------------------------------------
// K0: pre-split conv_w into 3 bf16 limb planes [lv][64][512] (192 KB total).
// ---------------------------------------------------------------------------
__global__ __launch_bounds__(256) void k_prep(
    const float* __restrict__ conv_w, unsigned short* __restrict__ cwL)
{
    const int i = blockIdx.x * 256 + threadIdx.x;
    const float4 v = *(const float4*)&conv_w[i * 4];
    const float vv[4] = {v.x, v.y, v.z, v.w};
    unsigned short h[4], m[4], l[4];
    #pragma unroll
    for (int j = 0; j < 4; ++j) split3(vv[j], h[j], m[j], l[j]);
    *(ushort4*)&cwL[0 * (K_ * D_) + i * 4] = make_ushort4(h[0], h[1], h[2], h[3]);
    *(ushort4*)&cwL[1 * (K_ * D_) + i * 4] = make_ushort4(m[0], m[1], m[2], m[3]);
    *(ushort4*)&cwL[2 * (K_ * D_) + i * 4] = make_ushort4(l[0], l[1], l[2], l[3]);
}

// ---------------------------------------------------------------------------
// K1: logits via 3-way-split bf16 MFMA + softmax + w limbs + fused wsum.
// EXACT baseline structure (237.4 us: cws LDS staging, 128n tile, grid 512,
// no launch-bounds hint). Single delta: w limbs stored as ONE interleaved
// uint plane (hi | lo<<16) -> epilogue stores halve (64x2B -> 32x4B per
// thread, 32B -> 64B segments). Bit-identical arithmetic.
// ---------------------------------------------------------------------------
__global__ __launch_bounds__(256) void k_logits_softmax(
    const float* __restrict__ x, const unsigned short* __restrict__ cwL,
    const float* __restrict__ conv_b,
    unsigned int* __restrict__ whl, float* __restrict__ wsumbuf)
{
    const int b   = blockIdx.x >> 5;
    const int n0  = (blockIdx.x & 31) * 128;
    const int tid  = threadIdx.x;
    const int w    = tid >> 6;
    const int lane = tid & 63;
    const int q = lane >> 4;
    const int c = lane & 15;
    const int ktb = (w & 1) * 32;
    const int ntb = (w >> 1) * 64;

    __shared__ unsigned short cws[3][64][40];   // [lvl][k][d]
    __shared__ unsigned short xs[3][128][40];   // [lvl][n][d-swizzled]
    __shared__ float redm[2][128];
    __shared__ float reds[2][128];

    f32x4 acc[2][4];
    #pragma unroll
    for (int kt = 0; kt < 2; ++kt)
        #pragma unroll
        for (int nt = 0; nt < 4; ++nt) acc[kt][nt] = (f32x4){0.f, 0.f, 0.f, 0.f};

    const float* xb = x + (size_t)b * D_ * N_ + n0;

    const int ks = tid >> 2;            // cw row
    const int d8 = (tid & 3) * 8;       // cw d-offset

    for (int d0 = 0; d0 < D_; d0 += 32) {
        // stage cw limbs: raw uint4 copies from pre-split planes
        #pragma unroll
        for (int lv = 0; lv < 3; ++lv)
            *(uint4*)&cws[lv][ks][d8] =
                *(const uint4*)&cwL[lv * (K_ * D_) + ks * D_ + d0 + d8];
        // stage x 32d x 128n transposed -> xs[n][d], split3, swizzled chunks
        #pragma unroll
        for (int i = 0; i < 4; ++i) {
            const int s  = i * 256 + tid;
            const int xn = s & 127;
            const int j  = s >> 7;                      // 8B chunk 0..7
            const int Cs = ((j >> 1) ^ ((xn >> 3) & 3)); // swizzled 16B chunk
            const int dsw = (Cs * 2 + (j & 1)) * 4;      // swizzled short offset
            const int dg4 = j * 4;                       // source d offset
            unsigned short h[4], m[4], l[4];
            #pragma unroll
            for (int r = 0; r < 4; ++r) {
                const float v = xb[(size_t)(d0 + dg4 + r) * N_ + xn];
                split3(v, h[r], m[r], l[r]);
            }
            *(ushort4*)&xs[0][xn][dsw] = make_ushort4(h[0], h[1], h[2], h[3]);
            *(ushort4*)&xs[1][xn][dsw] = make_ushort4(m[0], m[1], m[2], m[3]);
            *(ushort4*)&xs[2][xn][dsw] = make_ushort4(l[0], l[1], l[2], l[3]);
        }
        __syncthreads();

        bfrag af[2][3];
        #pragma unroll
        for (int kt = 0; kt < 2; ++kt)
            #pragma unroll
            for (int lv = 0; lv < 3; ++lv)
                af[kt][lv] = *(const bfrag*)&cws[lv][ktb + kt * 16 + c][q * 8];
        #pragma unroll
        for (int nt = 0; nt < 4; ++nt) {
            const int row = ntb + nt * 16 + c;
            const int qs  = (q ^ ((row >> 3) & 3)) * 8;  // swizzled read chunk
            bfrag bf[3];
            #pragma unroll
            for (int lv = 0; lv < 3; ++lv)
                bf[lv] = *(const bfrag*)&xs[lv][row][qs];
            #pragma unroll
            for (int kt = 0; kt < 2; ++kt) {
                f32x4 a = acc[kt][nt];
                a = MFMA(af[kt][0], bf[0], a);   // hh
                a = MFMA(af[kt][0], bf[1], a);   // hm
                a = MFMA(af[kt][1], bf[0], a);   // mh
                a = MFMA(af[kt][1], bf[1], a);   // mm
                a = MFMA(af[kt][0], bf[2], a);   // hl
                a = MFMA(af[kt][2], bf[0], a);   // lh
                acc[kt][nt] = a;
            }
        }
        __syncthreads();
    }

    // ---- bias + cross-wave softmax (lane owns k=ktb+kt*16+q*4+r, n=ntb+nt*16+c)
    #pragma unroll
    for (int kt = 0; kt < 2; ++kt)
        #pragma unroll
        for (int r = 0; r < 4; ++r) {
            const float bias = conv_b[ktb + kt * 16 + q * 4 + r];
            #pragma unroll
            for (int nt = 0; nt < 4; ++nt) acc[kt][nt][r] += bias;
        }

    float mloc[4];
    #pragma unroll
    for (int nt = 0; nt < 4; ++nt) {
        float m = acc[0][nt][0];
        #pragma unroll
        for (int kt = 0; kt < 2; ++kt)
            #pragma unroll
            for (int r = 0; r < 4; ++r) m = fmaxf(m, acc[kt][nt][r]);
        m = fmaxf(m, __shfl_xor(m, 16));
        m = fmaxf(m, __shfl_xor(m, 32));
        mloc[nt] = m;
    }
    if (q == 0)
        #pragma unroll
        for (int nt = 0; nt < 4; ++nt) redm[w & 1][ntb + nt * 16 + c] = mloc[nt];
    __syncthreads();
    float mall[4];
    #pragma unroll
    for (int nt = 0; nt < 4; ++nt)
        mall[nt] = fmaxf(redm[0][ntb + nt * 16 + c], redm[1][ntb + nt * 16 + c]);

    float sloc[4] = {0.f, 0.f, 0.f, 0.f};
    #pragma unroll
    for (int nt = 0; nt < 4; ++nt) {
        #pragma unroll
        for (int kt = 0; kt < 2; ++kt)
            #pragma unroll
            for (int r = 0; r < 4; ++r) {
                const float e = __expf(acc[kt][nt][r] - mall[nt]);
                acc[kt][nt][r] = e;
                sloc[nt] += e;
            }
        sloc[nt] += __shfl_xor(sloc[nt], 16);
        sloc[nt] += __shfl_xor(sloc[nt], 32);
    }
    if (q == 0)
        #pragma unroll
        for (int nt = 0; nt < 4; ++nt) reds[w & 1][ntb + nt * 16 + c] = sloc[nt];
    __syncthreads();

    float wacc[2][4] = {{0.f, 0.f, 0.f, 0.f}, {0.f, 0.f, 0.f, 0.f}};
    #pragma unroll
    for (int nt = 0; nt < 4; ++nt) {
        const float inv = 1.0f / (reds[0][ntb + nt * 16 + c] + reds[1][ntb + nt * 16 + c]);
        #pragma unroll
        for (int kt = 0; kt < 2; ++kt)
            #pragma unroll
            for (int r = 0; r < 4; ++r) {
                const float v = acc[kt][nt][r] * inv;
                unsigned short hi, lo;
                split2(v, hi, lo);
                const size_t idx = ((size_t)b * K_ + ktb + kt * 16 + q * 4 + r) * N_
                                 + n0 + ntb + nt * 16 + c;
                whl[idx] = (unsigned)hi | ((unsigned)lo << 16);
                wacc[kt][r] += v;
            }
    }
    // fused wsum: reduce over the 16 c-lanes, then one atomic per (k, wave)
    #pragma unroll
    for (int msk = 1; msk < 16; msk <<= 1)
        #pragma unroll
        for (int kt = 0; kt < 2; ++kt)
            #pragma unroll
            for (int r = 0; r < 4; ++r)
                wacc[kt][r] += __shfl_xor(wacc[kt][r], msk);
    if (c == 0)
        #pragma unroll
        for (int kt = 0; kt < 2; ++kt)
            #pragma unroll
            for (int r = 0; r < 4; ++r)
                atomicAdd(&wsumbuf[b * K_ + ktb + kt * 16 + q * 4 + r], wacc[kt][r]);
}

// ---------------------------------------------------------------------------
// K2: vlad += w . x^T via 2-way-split bf16 MFMA. EXACT baseline geometry
// (nc=8, grid 512, no launch-bounds hint). Single delta: w staged from the
// interleaved whl plane; de-interleave in-register at staging (same load
// bytes, LDS image bit-identical to baseline's ws2 planes).
// ---------------------------------------------------------------------------
__global__ __launch_bounds__(256) void k_wx(
    const float* __restrict__ x, const unsigned int* __restrict__ whl,
    float* __restrict__ vlad)
{
    const int nc = blockIdx.x & 7;
    const int dc = (blockIdx.x >> 3) & 3;
    const int b  = blockIdx.x >> 5;
    const int tid  = threadIdx.x;
    const int w    = tid >> 6;
    const int lane = tid & 63;
    const int q = lane >> 4;
    const int c = lane & 15;
    const int ktb = (w & 1) * 32;
    const int dtb = (w >> 1) * 64;

    __shared__ unsigned short ws2[2][64][40];    // [lvl][k][n]
    __shared__ unsigned short xs2[2][128][40];   // [lvl][d][n]

    f32x4 acc[2][4];
    #pragma unroll
    for (int kt = 0; kt < 2; ++kt)
        #pragma unroll
        for (int dt = 0; dt < 4; ++dt) acc[kt][dt] = (f32x4){0.f, 0.f, 0.f, 0.f};

    const float* xb = x + (size_t)b * D_ * N_ + (size_t)dc * 128 * N_;
    const unsigned int* wb = whl + (size_t)b * K_ * N_;

    const int wk = tid >> 2;            // w row
    const int wn = (tid & 3) * 8;       // w n-offset
    const int xd = tid >> 3;            // x row (i adds 32i)
    const int xn = (tid & 7) * 4;       // x n-offset

    const int nbase = nc * 512;
    for (int n0 = nbase; n0 < nbase + 512; n0 += 32) {
        {
            const uint4 a  = *(const uint4*)&wb[(size_t)wk * N_ + n0 + wn];
            const uint4 bq = *(const uint4*)&wb[(size_t)wk * N_ + n0 + wn + 4];
            bfrag h8, l8;
            h8[0] = (short)(unsigned short)a.x;  l8[0] = (short)(unsigned short)(a.x >> 16);
            h8[1] = (short)(unsigned short)a.y;  l8[1] = (short)(unsigned short)(a.y >> 16);
            h8[2] = (short)(unsigned short)a.z;  l8[2] = (short)(unsigned short)(a.z >> 16);
            h8[3] = (short)(unsigned short)a.w;  l8[3] = (short)(unsigned short)(a.w >> 16);
            h8[4] = (short)(unsigned short)bq.x; l8[4] = (short)(unsigned short)(bq.x >> 16);
            h8[5] = (short)(unsigned short)bq.y; l8[5] = (short)(unsigned short)(bq.y >> 16);
            h8[6] = (short)(unsigned short)bq.z; l8[6] = (short)(unsigned short)(bq.z >> 16);
            h8[7] = (short)(unsigned short)bq.w; l8[7] = (short)(unsigned short)(bq.w >> 16);
            *(bfrag*)&ws2[0][wk][wn] = h8;
            *(bfrag*)&ws2[1][wk][wn] = l8;
        }
        #pragma unroll
        for (int i = 0; i < 4; ++i) {
            const float4 v = *(const float4*)&xb[(size_t)(i * 32 + xd) * N_ + n0 + xn];
            const float vv[4] = {v.x, v.y, v.z, v.w};
            unsigned short h[4], l[4];
            #pragma unroll
            for (int j = 0; j < 4; ++j) split2(vv[j], h[j], l[j]);
            *(ushort4*)&xs2[0][i * 32 + xd][xn] = make_ushort4(h[0], h[1], h[2], h[3]);
            *(ushort4*)&xs2[1][i * 32 + xd][xn] = make_ushort4(l[0], l[1], l[2], l[3]);
        }
        __syncthreads();

        bfrag afh[2], afl[2];
        #pragma unroll
        for (int kt = 0; kt < 2; ++kt) {
            afh[kt] = *(const bfrag*)&ws2[0][ktb + kt * 16 + c][q * 8];
            afl[kt] = *(const bfrag*)&ws2[1][ktb + kt * 16 + c][q * 8];
        }
        #pragma unroll
        for (int dt = 0; dt < 4; ++dt) {
            const bfrag bh = *(const bfrag*)&xs2[0][dtb + dt * 16 + c][q * 8];
            const bfrag bl = *(const bfrag*)&xs2[1][dtb + dt * 16 + c][q * 8];
            #pragma unroll
            for (int kt = 0; kt < 2; ++kt) {
                f32x4 a = acc[kt][dt];
                a = MFMA(afh[kt], bh, a);
                a = MFMA(afh[kt], bl, a);
                a = MFMA(afl[kt], bh, a);
                acc[kt][dt] = a;
            }
        }
        __syncthreads();
    }

    #pragma unroll
    for (int kt = 0; kt < 2; ++kt)
        #pragma unroll
        for (int dt = 0; dt < 4; ++dt)
            #pragma unroll
            for (int r = 0; r < 4; ++r) {
                const int k = ktb + kt * 16 + q * 4 + r;
                const int d = dc * 128 + dtb + dt * 16 + c;
                atomicAdd(&vlad[((size_t)b * K_ + k) * D_ + d], acc[kt][dt][r]);
            }
}

// ---------------------------------------------------------------------------
// K3: v = vlad - wsum*c; row L2-norm; global norm = /8.  (wsum precomputed)
// ---------------------------------------------------------------------------
__global__ __launch_bounds__(256) void k_norm(
    const float* __restrict__ wsumbuf, const float* __restrict__ vlad,
    const float* __restrict__ centers, float* __restrict__ out)
{
    const int b = blockIdx.x >> 6;
    const int k = blockIdx.x & 63;
    const int tid = threadIdx.x;

    const float wsum = wsumbuf[b * K_ + k];

    const float* vr = vlad + ((size_t)b * K_ + k) * D_;
    const float* cr = centers + k * D_;
    const float v0 = vr[tid]       - wsum * cr[tid];
    const float v1 = vr[tid + 256] - wsum * cr[tid + 256];

    float ss = v0 * v0 + v1 * v1;
    __shared__ float red2[4];
    #pragma unroll
    for (int off = 32; off > 0; off >>= 1) ss += __shfl_down(ss, off, 64);
    if ((tid & 63) == 0) red2[tid >> 6] = ss;
    __syncthreads();
    const float nrm = sqrtf(red2[0] + red2[1] + red2[2] + red2[3]);
    const float scale = 1.0f / (8.0f * fmaxf(nrm, 1e-12f));

    float* outr = out + ((size_t)b * K_ + k) * D_;
    outr[tid]       = v0 * scale;
    outr[tid + 256] = v1 * scale;
}

extern "C" void kernel_launch(void* const* d_in, const int* in_sizes, int n_in,
                              void* d_out, int out_size, void* d_ws, size_t ws_size,
                              hipStream_t stream) {
    const float* x       = (const float*)d_in[0];
    const float* conv_w  = (const float*)d_in[1];
    const float* conv_b  = (const float*)d_in[2];
    const float* centers = (const float*)d_in[3];
    float* out = (float*)d_out;

    char* wsb = (char*)d_ws;
    float* vlad         = (float*)wsb;                          // 2 MiB
    float* wsumbuf      = (float*)(wsb + (2u << 20));           // 4 KiB
    unsigned int* whl   = (unsigned int*)(wsb + (3u << 20));    // 16 MiB
    unsigned short* cwL = (unsigned short*)(wsb + (20u << 20)); // 192 KiB

    hipMemsetAsync(vlad, 0, (2u << 20) + 4096, stream);

    k_prep<<<32, 256, 0, stream>>>(conv_w, cwL);
    k_logits_softmax<<<B_ * 32, 256, 0, stream>>>(x, cwL, conv_b, whl, wsumbuf);
    k_wx<<<B_ * 4 * 8, 256, 0, stream>>>(x, whl, vlad);
    k_norm<<<B_ * K_, 256, 0, stream>>>(wsumbuf, vlad, centers, out);
}